// Round 14
// baseline (117.145 us; speedup 1.0000x reference)
//
#include <hip/hip_runtime.h>
#include <math.h>

#define L2C 25
#define CH  128
#define NB  8
#define GLB 7
#define GLA 13
#define NG  91
#define GPAD 96
#define KPAD 32
#define HROWS 242

typedef short bf16x8 __attribute__((ext_vector_type(8)));
typedef int   i32x4  __attribute__((ext_vector_type(4)));
typedef float f32x4  __attribute__((ext_vector_type(4)));
typedef unsigned uint2v __attribute__((ext_vector_type(2)));

union frag_u { i32x4 i; bf16x8 h; };

__device__ inline short f2bf(float f) {
  union { float f; unsigned u; } v; v.f = f;
  unsigned r = (v.u + 0x7FFFu + ((v.u >> 16) & 1u)) >> 16;
  return (short)r;
}
__device__ inline unsigned cvt_pk_bf16(float lo, float hi) {
  unsigned r; asm("v_cvt_pk_bf16_f32 %0, %1, %2" : "=v"(r) : "v"(lo), "v"(hi)); return r;
}

// ---------------- SH tables (bf16), built on device (identical to R8/R13) ----------------
__global__ void build_tables_kernel(short* __restrict__ toT, short* __restrict__ frT) {
  const int g = threadIdx.x;
  if (g >= GPAD) return;
  const double PI = 3.14159265358979323846;
  double Y[L2C];
  double wg = 0.0;
  if (g < NG) {
    const int b = g / GLA;
    const int a = g % GLA;
    double xx = cos(PI * (b + 0.75) / (GLB + 0.5));
    double pp = 1.0;
    for (int it = 0; it < 64; ++it) {
      double p0 = 1.0, p1 = xx;
      for (int j = 2; j <= GLB; ++j) { double p2 = ((2.0*j-1.0)*xx*p1 - (j-1.0)*p0)/j; p0 = p1; p1 = p2; }
      pp = GLB * (xx*p1 - p0) / (xx*xx - 1.0);
      xx -= p1 / pp;
    }
    { double p0 = 1.0, p1 = xx;
      for (int j = 2; j <= GLB; ++j) { double p2 = ((2.0*j-1.0)*xx*p1 - (j-1.0)*p0)/j; p0 = p1; p1 = p2; }
      pp = GLB * (xx*p1 - p0) / (xx*xx - 1.0); }
    const double wb = 2.0 / ((1.0 - xx*xx) * pp * pp);
    const double ct = xx;
    const double sx = sqrt(fmax(0.0, 1.0 - ct*ct));
    double P[5][5];
    P[0][0] = 1.0;
    for (int m = 1; m <= 4; ++m) P[m][m] = -(2.0*m - 1.0) * sx * P[m-1][m-1];
    for (int m = 0; m <= 3; ++m) P[m+1][m] = (2.0*m + 1.0) * ct * P[m][m];
    for (int m = 0; m <= 4; ++m)
      for (int l = m + 2; l <= 4; ++l)
        P[l][m] = ((2.0*l-1.0)*ct*P[l-1][m] - (l+m-1.0)*P[l-2][m]) / (l - m);
    const double fact[9] = {1,1,2,6,24,120,720,5040,40320};
    const double phi = (2.0*PI/GLA) * a;
    for (int l = 0; l <= 4; ++l)
      for (int m = 0; m <= l; ++m) {
        double Nlm = sqrt((2.0*l+1.0)/(4.0*PI) * fact[l-m]/fact[l+m]);
        if (m == 0) Y[l*l + l] = Nlm * P[l][0];
        else {
          double base = sqrt(2.0) * Nlm * P[l][m];
          Y[l*l + l + m] = base * cos((double)m * phi);
          Y[l*l + l - m] = base * sin((double)m * phi);
        }
      }
    wg = wb * (2.0*PI/GLA);
  }
  for (int l = 0; l < KPAD; ++l) {
    float tv = (g < NG && l < L2C) ? (float)Y[l] : 0.f;
    toT[g*KPAD + l] = f2bf(tv);
  }
  {
    const int hi = g >> 4, r = g & 15;
    const int ksv = hi >> 1, pa = hi & 1;
    const int lqv = r >> 2,  pb = r & 3;
    const int kg = ksv*32 + lqv*8 + pa*4 + pb;
    for (int l = 0; l < KPAD; ++l)
      frT[l*GPAD + kg] = (g < NG && l < L2C) ? f2bf((float)(wg * Y[l])) : (short)0;
  }
}

__global__ void convert_w_kernel(const float* __restrict__ w1, const float* __restrict__ w2,
                                 short* __restrict__ wb1, short* __restrict__ wb2) {
  const int i = blockIdx.x * 256 + threadIdx.x;
  if (i < 5*CH*CH) { wb1[i] = f2bf(w1[i]); wb2[i] = f2bf(w2[i]); }
}

// ==== R13 structure + latency motion: table-load hoist, lin2 per-degree batch + x prefetch ====
__global__ __launch_bounds__(512, 4) void eqv3_fused8u(
    const float* __restrict__ x,
    const float* __restrict__ norm_w, const float* __restrict__ norm_b,
    const short* __restrict__ wb1, const float* __restrict__ b1,
    const float* __restrict__ w_tp,
    const short* __restrict__ wb2, const float* __restrict__ b2,
    const short* __restrict__ toT, const short* __restrict__ frT,
    float* __restrict__ out)
{
  __shared__ __align__(16) short u[32768];            // 65,536 B single buffer
  short (*hsh)[HROWS][8] = (short (*)[HROWS][8])u;    // view A: [16][242][8]  (61,952 B)
  short (*hg)[4][CH][8]  = (short (*)[4][CH][8])u;    // view B: [8][4][128][8] (65,536 B)

  const int tid  = threadIdx.x;
  const int w    = tid >> 6;
  const int lane = tid & 63;
  const int l16  = lane & 15;
  const int lq   = lane >> 4;
  const long n0  = (long)blockIdx.x * NB;
  const int k    = w*16 + l16;    // this wave's channel column

  constexpr int LDEG[L2C] = {0,1,1,1,2,2,2,2,2,3,3,3,3,3,3,3,4,4,4,4,4,4,4,4,4};
  constexpr int BROW[5]   = {0,16,48,96,160};   // rows = (s-d*d)*8 + node
  constexpr int NT[5]     = {1,2,3,4,5};        // 16-row M-tiles per degree (15 total)

  // ---- LayerNorm: wave w owns node w; x read ONCE as float4 (proven R8/R13) ----
  {
    const float4* x4 = (const float4*)(x + (n0 + w)*(long)(L2C*CH));
    float4 xv[13];
    float s0 = 0.f, s0q = 0.f, sq = 0.f;
    #pragma unroll
    for (int it = 0; it < 13; ++it) {
      const int j = it*64 + lane;
      if (j < 800) {
        xv[it] = x4[j];
        const float t = xv[it].x*xv[it].x + xv[it].y*xv[it].y + xv[it].z*xv[it].z + xv[it].w*xv[it].w;
        if (j < 32) { s0 += xv[it].x + xv[it].y + xv[it].z + xv[it].w; s0q += t; }
        else        sq += t;
      }
    }
    #pragma unroll
    for (int o = 1; o < 64; o <<= 1) {
      s0  += __shfl_xor(s0,  o, 64);
      s0q += __shfl_xor(s0q, o, 64);
      sq  += __shfl_xor(sq,  o, 64);
    }
    const float mean0 = s0 * (1.f/CH);
    const float var   = (sq + s0q - CH*mean0*mean0) * (1.f/(L2C*CH));
    const float rstd  = rsqrtf(var + 1e-5f);
    #pragma unroll
    for (int it = 0; it < 13; ++it) {
      const int j = it*64 + lane;
      if (j < 800) {
        const int s = j >> 5;
        const int d = (int)sqrtf((float)s + 0.5f);  // exact floor-sqrt for s<25
        const int row = 8*(s + d) + w;              // == BROW[d] + (s-d*d)*8 + w
        const int c32 = j & 31;
        const int c0  = c32 * 4;
        const float4 nw4 = ((const float4*)norm_w)[d*32 + c32];
        float a0 = xv[it].x, a1 = xv[it].y, a2 = xv[it].z, a3 = xv[it].w;
        if (s == 0) {
          const float4 nb4 = ((const float4*)norm_b)[c32];
          a0 = (a0 - mean0)*rstd*nw4.x + nb4.x;
          a1 = (a1 - mean0)*rstd*nw4.y + nb4.y;
          a2 = (a2 - mean0)*rstd*nw4.z + nb4.z;
          a3 = (a3 - mean0)*rstd*nw4.w + nb4.w;
        } else {
          a0 *= rstd*nw4.x; a1 *= rstd*nw4.y; a2 *= rstd*nw4.z; a3 *= rstd*nw4.w;
        }
        uint2v pk; pk[0] = cvt_pk_bf16(a0, a1); pk[1] = cvt_pk_bf16(a2, a3);
        *(uint2v*)&hsh[c0 >> 3][row][c0 & 7] = pk;
      }
    }
  }
  __syncthreads();   // (1) LN staged in buffer (hsh view)

  // ---- linear1: accumulate ALL 15 tiles into packed bf16 pairs (reads only) ----
  unsigned pk1[15][2];
  {
    const float b1k = b1[k];
    int t = 0;
    #pragma unroll
    for (int d = 0; d < 5; ++d) {
      frag_u B[4];
      #pragma unroll
      for (int ks = 0; ks < 4; ++ks)
        B[ks].i = *(const i32x4*)(wb1 + ((d*CH + k)*CH + ks*32 + lq*8));
      #pragma unroll
      for (int mt = 0; mt < NT[d]; ++mt, ++t) {
        f32x4 acc = {0.f, 0.f, 0.f, 0.f};
        #pragma unroll
        for (int ks = 0; ks < 4; ++ks) {
          const bf16x8 a = *(const bf16x8*)&hsh[ks*4 + lq][BROW[d] + mt*16 + l16][0];
          acc = __builtin_amdgcn_mfma_f32_16x16x32_bf16(a, B[ks].h, acc, 0, 0, 0);
        }
        const int sl = 2*mt + (lq >> 1);
        const float bb = ((d == 0) & (sl == 0)) ? b1k : 0.f;
        pk1[t][0] = cvt_pk_bf16(acc[0] + bb, acc[1] + bb);
        pk1[t][1] = cvt_pk_bf16(acc[2] + bb, acc[3] + bb);
      }
    }
  }
  __syncthreads();   // (2) ALL lin1 reads complete; buffer reusable in hg view

  // ---- HOISTED Gaunt constants: issue global table loads now, hide under hg writes ----
  frag_u Ato[6];
  #pragma unroll
  for (int gt = 0; gt < 6; ++gt)
    Ato[gt].i = *(const i32x4*)(toT + (gt*16 + l16)*KPAD + lq*8);
  frag_u Afr[2][3];
  #pragma unroll
  for (int mt = 0; mt < 2; ++mt)
    #pragma unroll
    for (int ks = 0; ks < 3; ++ks)
      Afr[mt][ks].i = *(const i32x4*)(frT + (mt*16 + l16)*GPAD + ks*32 + lq*8);
  float wtp[2][4]; int hrowb[2][4];
  #pragma unroll
  for (int mt = 0; mt < 2; ++mt)
    #pragma unroll
    for (int i = 0; i < 4; ++i) {
      const int l = mt*16 + lq*4 + i;
      if (l < L2C) {
        const int d = LDEG[l];
        wtp[mt][i]   = w_tp[d*CH + k];
        hrowb[mt][i] = BROW[d] + (l - d*d)*NB;
      } else { wtp[mt][i] = 0.f; hrowb[mt][i] = -1; }
    }

  // ---- write lin1 output (hg view, wave-private k columns) ----
  {
    const i32x4 z = {0,0,0,0};
    #pragma unroll
    for (int n = 0; n < NB; ++n) *(i32x4*)&hg[n][3][k][0] = z;   // slots 24..31 hygiene
    int t = 0;
    #pragma unroll
    for (int d = 0; d < 5; ++d)
      #pragma unroll
      for (int mt = 0; mt < NT[d]; ++mt, ++t) {
        const int sl = 2*mt + (lq >> 1);
        if (sl <= 2*d) {
          const int s  = d*d + sl;
          const int nb = (lq & 1)*4;
          hg[nb+0][s >> 3][k][s & 7] = (short)(pk1[t][0] & 0xFFFFu);
          hg[nb+1][s >> 3][k][s & 7] = (short)(pk1[t][0] >> 16);
          hg[nb+2][s >> 3][k][s & 7] = (short)(pk1[t][1] & 0xFFFFu);
          hg[nb+3][s >> 3][k][s & 7] = (short)(pk1[t][1] >> 16);
        }
      }
  }

  // ---- Bh prefetch: own k columns (this wave wrote them; no barrier needed) ----
  frag_u Bh[NB];
  #pragma unroll
  for (int n = 0; n < NB; ++n)
    Bh[n].i = *(const i32x4*)&hg[n][lq][k][0];
  __syncthreads();   // (3) all hg reads done; Gaunt may write buffer in hsh view

  // ---- Gaunt: 2 independent node streams; register from-grid handoff (proven R8) ----
  {
    #pragma unroll
    for (int np = 0; np < 4; ++np) {
      const int nA = np, nB2 = np + 4;
      unsigned pA[6][2], pB[6][2];
      #pragma unroll
      for (int gt = 0; gt < 6; ++gt) {
        f32x4 aA = {0.f,0.f,0.f,0.f}, aB = {0.f,0.f,0.f,0.f};
        aA = __builtin_amdgcn_mfma_f32_16x16x32_bf16(Ato[gt].h, Bh[nA].h,  aA, 0, 0, 0);
        aB = __builtin_amdgcn_mfma_f32_16x16x32_bf16(Ato[gt].h, Bh[nB2].h, aB, 0, 0, 0);
        pA[gt][0] = cvt_pk_bf16(aA[0]*aA[0], aA[1]*aA[1]);
        pA[gt][1] = cvt_pk_bf16(aA[2]*aA[2], aA[3]*aA[3]);
        pB[gt][0] = cvt_pk_bf16(aB[0]*aB[0], aB[1]*aB[1]);
        pB[gt][1] = cvt_pk_bf16(aB[2]*aB[2], aB[3]*aB[3]);
      }
      f32x4 acc2A[2] = {{0.f,0.f,0.f,0.f},{0.f,0.f,0.f,0.f}};
      f32x4 acc2B[2] = {{0.f,0.f,0.f,0.f},{0.f,0.f,0.f,0.f}};
      #pragma unroll
      for (int ks = 0; ks < 3; ++ks) {
        frag_u BgA, BgB;
        BgA.i[0] = (int)pA[2*ks][0];   BgA.i[1] = (int)pA[2*ks][1];
        BgA.i[2] = (int)pA[2*ks+1][0]; BgA.i[3] = (int)pA[2*ks+1][1];
        BgB.i[0] = (int)pB[2*ks][0];   BgB.i[1] = (int)pB[2*ks][1];
        BgB.i[2] = (int)pB[2*ks+1][0]; BgB.i[3] = (int)pB[2*ks+1][1];
        acc2A[0] = __builtin_amdgcn_mfma_f32_16x16x32_bf16(Afr[0][ks].h, BgA.h, acc2A[0], 0, 0, 0);
        acc2A[1] = __builtin_amdgcn_mfma_f32_16x16x32_bf16(Afr[1][ks].h, BgA.h, acc2A[1], 0, 0, 0);
        acc2B[0] = __builtin_amdgcn_mfma_f32_16x16x32_bf16(Afr[0][ks].h, BgB.h, acc2B[0], 0, 0, 0);
        acc2B[1] = __builtin_amdgcn_mfma_f32_16x16x32_bf16(Afr[1][ks].h, BgB.h, acc2B[1], 0, 0, 0);
      }
      #pragma unroll
      for (int mt = 0; mt < 2; ++mt)
        #pragma unroll
        for (int i = 0; i < 4; ++i)
          if (hrowb[mt][i] >= 0) {
            hsh[k >> 3][hrowb[mt][i] + nA][k & 7]  = f2bf(acc2A[mt][i] * wtp[mt][i]);
            hsh[k >> 3][hrowb[mt][i] + nB2][k & 7] = f2bf(acc2B[mt][i] * wtp[mt][i]);
          }
    }
  }
  __syncthreads();   // (4) Gaunt output staged (hsh view)

  // ---- linear2: per-degree batched A-reads + x-residual prefetch, then MFMA + store ----
  {
    const float b2k = b2[k];
    #pragma unroll
    for (int d = 0; d < 5; ++d) {
      frag_u B[4];
      #pragma unroll
      for (int ks = 0; ks < 4; ++ks)
        B[ks].i = *(const i32x4*)(wb2 + ((d*CH + k)*CH + ks*32 + lq*8));
      // batch-issue all A-frag ds_reads for this degree
      frag_u A[5][4];
      #pragma unroll
      for (int mt = 0; mt < NT[d]; ++mt)
        #pragma unroll
        for (int ks = 0; ks < 4; ++ks)
          A[mt][ks].h = *(const bf16x8*)&hsh[ks*4 + lq][BROW[d] + mt*16 + l16][0];
      // batch-issue residual x loads for this degree (latency hides under MFMAs)
      float xr[5][4];
      #pragma unroll
      for (int mt = 0; mt < NT[d]; ++mt) {
        const int sl = 2*mt + (lq >> 1);
        if (sl <= 2*d) {
          const int s = d*d + sl;
          #pragma unroll
          for (int i = 0; i < 4; ++i) {
            const int node = (lq & 1)*4 + i;
            xr[mt][i] = x[(n0 + node)*(long)(L2C*CH) + s*CH + k];
          }
        }
      }
      // MFMA + add + store
      #pragma unroll
      for (int mt = 0; mt < NT[d]; ++mt) {
        f32x4 acc = {0.f, 0.f, 0.f, 0.f};
        #pragma unroll
        for (int ks = 0; ks < 4; ++ks)
          acc = __builtin_amdgcn_mfma_f32_16x16x32_bf16(A[mt][ks].h, B[ks].h, acc, 0, 0, 0);
        const int sl = 2*mt + (lq >> 1);
        if (sl <= 2*d) {
          const int s = d*d + sl;
          #pragma unroll
          for (int i = 0; i < 4; ++i) {
            const int node = (lq & 1)*4 + i;
            const long base = (n0 + node)*(long)(L2C*CH) + s*CH + k;
            out[base] = acc[i] + ((s == 0) ? b2k : 0.f) + xr[mt][i];
          }
        }
      }
    }
  }
}

// ---------------- launch ----------------
extern "C" void kernel_launch(void* const* d_in, const int* in_sizes, int n_in,
                              void* d_out, int out_size, void* d_ws, size_t ws_size,
                              hipStream_t stream) {
  const float* x      = (const float*)d_in[0];
  // d_in[1] = batch (unused)
  const float* norm_w = (const float*)d_in[2];
  const float* norm_b = (const float*)d_in[3];
  const float* w1     = (const float*)d_in[4];
  const float* b1     = (const float*)d_in[5];
  const float* w_tp   = (const float*)d_in[6];
  const float* w2     = (const float*)d_in[7];
  const float* b2     = (const float*)d_in[8];
  float* out = (float*)d_out;

  const int N = in_sizes[0] / (L2C*CH);   // 6000

  short* wsS = (short*)d_ws;              // ~340 KB
  short* toT = wsS;                       // [96][32]
  short* frT = toT + GPAD*KPAD;           // [32][96]
  short* wb1 = frT + KPAD*GPAD;           // [5][128][128]
  short* wb2 = wb1 + 5*CH*CH;

  build_tables_kernel<<<1, 128, 0, stream>>>(toT, frT);
  convert_w_kernel<<<(5*CH*CH + 255)/256, 256, 0, stream>>>(w1, w2, wb1, wb2);
  eqv3_fused8u<<<N/NB, 512, 0, stream>>>(x, norm_w, norm_b, wb1, b1, w_tp, wb2, b2, toT, frT, out);
}

// Round 15
// 107.284 us; speedup vs baseline: 1.0919x; 1.0919x over previous
//
#include <hip/hip_runtime.h>
#include <math.h>

#define L2C 25
#define CH  128
#define NB  16
#define GLB 7
#define GLA 13
#define NG  91
#define GPAD 96
#define KPAD 32
#define HROWS 401   // 400 used rows (=16*25) + 1 pad row to stagger quad banks

typedef short bf16x8 __attribute__((ext_vector_type(8)));
typedef int   i32x4  __attribute__((ext_vector_type(4)));
typedef float f32x4  __attribute__((ext_vector_type(4)));
typedef unsigned uint2v __attribute__((ext_vector_type(2)));

union frag_u { i32x4 i; bf16x8 h; };

__device__ inline short f2bf(float f) {
  union { float f; unsigned u; } v; v.f = f;
  unsigned r = (v.u + 0x7FFFu + ((v.u >> 16) & 1u)) >> 16;
  return (short)r;
}
__device__ inline unsigned cvt_pk_bf16(float lo, float hi) {
  unsigned r; asm("v_cvt_pk_bf16_f32 %0, %1, %2" : "=v"(r) : "v"(lo), "v"(hi)); return r;
}

// ---------------- SH tables (bf16), built on device (identical to R8/R13) ----------------
__global__ void build_tables_kernel(short* __restrict__ toT, short* __restrict__ frT) {
  const int g = threadIdx.x;
  if (g >= GPAD) return;
  const double PI = 3.14159265358979323846;
  double Y[L2C];
  double wg = 0.0;
  if (g < NG) {
    const int b = g / GLA;
    const int a = g % GLA;
    double xx = cos(PI * (b + 0.75) / (GLB + 0.5));
    double pp = 1.0;
    for (int it = 0; it < 64; ++it) {
      double p0 = 1.0, p1 = xx;
      for (int j = 2; j <= GLB; ++j) { double p2 = ((2.0*j-1.0)*xx*p1 - (j-1.0)*p0)/j; p0 = p1; p1 = p2; }
      pp = GLB * (xx*p1 - p0) / (xx*xx - 1.0);
      xx -= p1 / pp;
    }
    { double p0 = 1.0, p1 = xx;
      for (int j = 2; j <= GLB; ++j) { double p2 = ((2.0*j-1.0)*xx*p1 - (j-1.0)*p0)/j; p0 = p1; p1 = p2; }
      pp = GLB * (xx*p1 - p0) / (xx*xx - 1.0); }
    const double wb = 2.0 / ((1.0 - xx*xx) * pp * pp);
    const double ct = xx;
    const double sx = sqrt(fmax(0.0, 1.0 - ct*ct));
    double P[5][5];
    P[0][0] = 1.0;
    for (int m = 1; m <= 4; ++m) P[m][m] = -(2.0*m - 1.0) * sx * P[m-1][m-1];
    for (int m = 0; m <= 3; ++m) P[m+1][m] = (2.0*m + 1.0) * ct * P[m][m];
    for (int m = 0; m <= 4; ++m)
      for (int l = m + 2; l <= 4; ++l)
        P[l][m] = ((2.0*l-1.0)*ct*P[l-1][m] - (l+m-1.0)*P[l-2][m]) / (l - m);
    const double fact[9] = {1,1,2,6,24,120,720,5040,40320};
    const double phi = (2.0*PI/GLA) * a;
    for (int l = 0; l <= 4; ++l)
      for (int m = 0; m <= l; ++m) {
        double Nlm = sqrt((2.0*l+1.0)/(4.0*PI) * fact[l-m]/fact[l+m]);
        if (m == 0) Y[l*l + l] = Nlm * P[l][0];
        else {
          double base = sqrt(2.0) * Nlm * P[l][m];
          Y[l*l + l + m] = base * cos((double)m * phi);
          Y[l*l + l - m] = base * sin((double)m * phi);
        }
      }
    wg = wb * (2.0*PI/GLA);
  }
  for (int l = 0; l < KPAD; ++l) {
    float tv = (g < NG && l < L2C) ? (float)Y[l] : 0.f;
    toT[g*KPAD + l] = f2bf(tv);
  }
  {
    const int hi = g >> 4, r = g & 15;
    const int ksv = hi >> 1, pa = hi & 1;
    const int lqv = r >> 2,  pb = r & 3;
    const int kg = ksv*32 + lqv*8 + pa*4 + pb;
    for (int l = 0; l < KPAD; ++l)
      frT[l*GPAD + kg] = (g < NG && l < L2C) ? f2bf((float)(wg * Y[l])) : (short)0;
  }
}

__global__ void convert_w_kernel(const float* __restrict__ w1, const float* __restrict__ w2,
                                 short* __restrict__ wb1, short* __restrict__ wb2) {
  const int i = blockIdx.x * 256 + threadIdx.x;
  if (i < 5*CH*CH) { wb1[i] = f2bf(w1[i]); wb2[i] = f2bf(w2[i]); }
}

// ==== NB=16: row = 16*s + node (zero padding); aliased buffer; deferred lin1 writes ====
__global__ __launch_bounds__(512, 2) void eqv3_fused16(
    const float* __restrict__ x,
    const float* __restrict__ norm_w, const float* __restrict__ norm_b,
    const short* __restrict__ wb1, const float* __restrict__ b1,
    const float* __restrict__ w_tp,
    const short* __restrict__ wb2, const float* __restrict__ b2,
    const short* __restrict__ toT, const short* __restrict__ frT,
    float* __restrict__ out)
{
  __shared__ __align__(16) short u[65536];            // 131,072 B single buffer
  short (*hsh)[HROWS][8] = (short (*)[HROWS][8])u;    // view A: [16][401][8]  (102,656 B)
  short (*hg)[4][CH][8]  = (short (*)[4][CH][8])u;    // view B: [16][4][128][8] (131,072 B)

  const int tid  = threadIdx.x;
  const int w    = tid >> 6;
  const int lane = tid & 63;
  const int l16  = lane & 15;
  const int lq   = lane >> 4;
  const long n0  = (long)blockIdx.x * NB;
  const int k    = w*16 + l16;    // this wave's channel column

  constexpr int LDEG[L2C] = {0,1,1,1,2,2,2,2,2,3,3,3,3,3,3,3,4,4,4,4,4,4,4,4,4};
  constexpr int NT[5]     = {1,3,5,7,9};   // tiles per degree == slots per degree (no padding)

  // ---- LayerNorm: wave w handles nodes w and w+8 (sequential); x read once/node ----
  #pragma unroll
  for (int rep = 0; rep < 2; ++rep) {
    const int node = w + rep*8;
    const float4* x4 = (const float4*)(x + (n0 + node)*(long)(L2C*CH));
    float4 xv[13];
    float s0 = 0.f, s0q = 0.f, sq = 0.f;
    #pragma unroll
    for (int it = 0; it < 13; ++it) {
      const int j = it*64 + lane;
      if (j < 800) {
        xv[it] = x4[j];
        const float t = xv[it].x*xv[it].x + xv[it].y*xv[it].y + xv[it].z*xv[it].z + xv[it].w*xv[it].w;
        if (j < 32) { s0 += xv[it].x + xv[it].y + xv[it].z + xv[it].w; s0q += t; }
        else        sq += t;
      }
    }
    #pragma unroll
    for (int o = 1; o < 64; o <<= 1) {
      s0  += __shfl_xor(s0,  o, 64);
      s0q += __shfl_xor(s0q, o, 64);
      sq  += __shfl_xor(sq,  o, 64);
    }
    const float mean0 = s0 * (1.f/CH);
    const float var   = (sq + s0q - CH*mean0*mean0) * (1.f/(L2C*CH));
    const float rstd  = rsqrtf(var + 1e-5f);
    #pragma unroll
    for (int it = 0; it < 13; ++it) {
      const int j = it*64 + lane;
      if (j < 800) {
        const int s = j >> 5;
        const int d = (int)sqrtf((float)s + 0.5f);  // exact floor-sqrt for s<25
        const int row = 16*s + node;                // NB=16: natural [s][node] layout
        const int c32 = j & 31;
        const int c0  = c32 * 4;
        const float4 nw4 = ((const float4*)norm_w)[d*32 + c32];
        float a0 = xv[it].x, a1 = xv[it].y, a2 = xv[it].z, a3 = xv[it].w;
        if (s == 0) {
          const float4 nb4 = ((const float4*)norm_b)[c32];
          a0 = (a0 - mean0)*rstd*nw4.x + nb4.x;
          a1 = (a1 - mean0)*rstd*nw4.y + nb4.y;
          a2 = (a2 - mean0)*rstd*nw4.z + nb4.z;
          a3 = (a3 - mean0)*rstd*nw4.w + nb4.w;
        } else {
          a0 *= rstd*nw4.x; a1 *= rstd*nw4.y; a2 *= rstd*nw4.z; a3 *= rstd*nw4.w;
        }
        uint2v pk; pk[0] = cvt_pk_bf16(a0, a1); pk[1] = cvt_pk_bf16(a2, a3);
        *(uint2v*)&hsh[c0 >> 3][row][c0 & 7] = pk;
      }
    }
  }
  __syncthreads();   // (1) LN staged (all 400 rows written; no pad rows exist)

  // ---- linear1: 25 full tiles (tile == slot), accumulate packed bf16 pairs ----
  unsigned pk1[L2C][2];
  {
    const float b1k = b1[k];
    int s = 0;
    #pragma unroll
    for (int d = 0; d < 5; ++d) {
      frag_u B[4];
      #pragma unroll
      for (int ks = 0; ks < 4; ++ks)
        B[ks].i = *(const i32x4*)(wb1 + ((d*CH + k)*CH + ks*32 + lq*8));
      #pragma unroll
      for (int mt = 0; mt < NT[d]; ++mt, ++s) {
        f32x4 acc = {0.f, 0.f, 0.f, 0.f};
        #pragma unroll
        for (int ks = 0; ks < 4; ++ks) {
          const bf16x8 a = *(const bf16x8*)&hsh[ks*4 + lq][16*s + l16][0];
          acc = __builtin_amdgcn_mfma_f32_16x16x32_bf16(a, B[ks].h, acc, 0, 0, 0);
        }
        const float bb = (s == 0) ? b1k : 0.f;
        pk1[s][0] = cvt_pk_bf16(acc[0] + bb, acc[1] + bb);
        pk1[s][1] = cvt_pk_bf16(acc[2] + bb, acc[3] + bb);
      }
    }
  }
  __syncthreads();   // (2) ALL lin1 reads complete; buffer reusable in hg view

  // ---- write lin1 output (hg view); lane owns nodes lq*4..lq*4+3, column k ----
  {
    const i32x4 z = {0,0,0,0};
    #pragma unroll
    for (int j = 0; j < 4; ++j)
      *(i32x4*)&hg[lq*4 + j][3][k][0] = z;   // zero slots 24..31 for OWN nodes (24 rewritten below)
    #pragma unroll
    for (int s = 0; s < L2C; ++s) {
      const int nb = lq*4;
      hg[nb+0][s >> 3][k][s & 7] = (short)(pk1[s][0] & 0xFFFFu);
      hg[nb+1][s >> 3][k][s & 7] = (short)(pk1[s][0] >> 16);
      hg[nb+2][s >> 3][k][s & 7] = (short)(pk1[s][1] & 0xFFFFu);
      hg[nb+3][s >> 3][k][s & 7] = (short)(pk1[s][1] >> 16);
    }
  }

  // ---- Bh prefetch: own k columns (written by this wave's lanes; no barrier needed) ----
  frag_u Bh[NB];
  #pragma unroll
  for (int n = 0; n < NB; ++n)
    Bh[n].i = *(const i32x4*)&hg[n][lq][k][0];
  __syncthreads();   // (3) all hg reads done; Gaunt may write buffer in hsh view

  // ---- Gaunt: 2 independent node streams (n, n+8); register from-grid handoff (R8) ----
  {
    frag_u Ato[6];
    #pragma unroll
    for (int gt = 0; gt < 6; ++gt)
      Ato[gt].i = *(const i32x4*)(toT + (gt*16 + l16)*KPAD + lq*8);
    frag_u Afr[2][3];
    #pragma unroll
    for (int mt = 0; mt < 2; ++mt)
      #pragma unroll
      for (int ks = 0; ks < 3; ++ks)
        Afr[mt][ks].i = *(const i32x4*)(frT + (mt*16 + l16)*GPAD + ks*32 + lq*8);

    float wtp[2][4]; int hrowb[2][4];
    #pragma unroll
    for (int mt = 0; mt < 2; ++mt)
      #pragma unroll
      for (int i = 0; i < 4; ++i) {
        const int l = mt*16 + lq*4 + i;
        if (l < L2C) {
          wtp[mt][i]   = w_tp[LDEG[l]*CH + k];
          hrowb[mt][i] = 16*l;                 // NB=16: row = 16*l + node
        } else { wtp[mt][i] = 0.f; hrowb[mt][i] = -1; }
      }

    #pragma unroll
    for (int np = 0; np < 8; ++np) {
      const int nA = np, nB2 = np + 8;
      unsigned pA[6][2], pB[6][2];
      #pragma unroll
      for (int gt = 0; gt < 6; ++gt) {
        f32x4 aA = {0.f,0.f,0.f,0.f}, aB = {0.f,0.f,0.f,0.f};
        aA = __builtin_amdgcn_mfma_f32_16x16x32_bf16(Ato[gt].h, Bh[nA].h,  aA, 0, 0, 0);
        aB = __builtin_amdgcn_mfma_f32_16x16x32_bf16(Ato[gt].h, Bh[nB2].h, aB, 0, 0, 0);
        pA[gt][0] = cvt_pk_bf16(aA[0]*aA[0], aA[1]*aA[1]);
        pA[gt][1] = cvt_pk_bf16(aA[2]*aA[2], aA[3]*aA[3]);
        pB[gt][0] = cvt_pk_bf16(aB[0]*aB[0], aB[1]*aB[1]);
        pB[gt][1] = cvt_pk_bf16(aB[2]*aB[2], aB[3]*aB[3]);
      }
      f32x4 acc2A[2] = {{0.f,0.f,0.f,0.f},{0.f,0.f,0.f,0.f}};
      f32x4 acc2B[2] = {{0.f,0.f,0.f,0.f},{0.f,0.f,0.f,0.f}};
      #pragma unroll
      for (int ks = 0; ks < 3; ++ks) {
        frag_u BgA, BgB;
        BgA.i[0] = (int)pA[2*ks][0];   BgA.i[1] = (int)pA[2*ks][1];
        BgA.i[2] = (int)pA[2*ks+1][0]; BgA.i[3] = (int)pA[2*ks+1][1];
        BgB.i[0] = (int)pB[2*ks][0];   BgB.i[1] = (int)pB[2*ks][1];
        BgB.i[2] = (int)pB[2*ks+1][0]; BgB.i[3] = (int)pB[2*ks+1][1];
        acc2A[0] = __builtin_amdgcn_mfma_f32_16x16x32_bf16(Afr[0][ks].h, BgA.h, acc2A[0], 0, 0, 0);
        acc2A[1] = __builtin_amdgcn_mfma_f32_16x16x32_bf16(Afr[1][ks].h, BgA.h, acc2A[1], 0, 0, 0);
        acc2B[0] = __builtin_amdgcn_mfma_f32_16x16x32_bf16(Afr[0][ks].h, BgB.h, acc2B[0], 0, 0, 0);
        acc2B[1] = __builtin_amdgcn_mfma_f32_16x16x32_bf16(Afr[1][ks].h, BgB.h, acc2B[1], 0, 0, 0);
      }
      #pragma unroll
      for (int mt = 0; mt < 2; ++mt)
        #pragma unroll
        for (int i = 0; i < 4; ++i)
          if (hrowb[mt][i] >= 0) {
            hsh[k >> 3][hrowb[mt][i] + nA][k & 7]  = f2bf(acc2A[mt][i] * wtp[mt][i]);
            hsh[k >> 3][hrowb[mt][i] + nB2][k & 7] = f2bf(acc2B[mt][i] * wtp[mt][i]);
          }
    }
  }
  __syncthreads();   // (4) Gaunt output staged (hsh view)

  // ---- linear2: 25 full tiles + bias(l=0) + residual -> direct global store ----
  {
    const float b2k = b2[k];
    int s = 0;
    #pragma unroll
    for (int d = 0; d < 5; ++d) {
      frag_u B[4];
      #pragma unroll
      for (int ks = 0; ks < 4; ++ks)
        B[ks].i = *(const i32x4*)(wb2 + ((d*CH + k)*CH + ks*32 + lq*8));
      #pragma unroll
      for (int mt = 0; mt < NT[d]; ++mt, ++s) {
        f32x4 acc = {0.f, 0.f, 0.f, 0.f};
        #pragma unroll
        for (int ks = 0; ks < 4; ++ks) {
          const bf16x8 a = *(const bf16x8*)&hsh[ks*4 + lq][16*s + l16][0];
          acc = __builtin_amdgcn_mfma_f32_16x16x32_bf16(a, B[ks].h, acc, 0, 0, 0);
        }
        const float bb = (s == 0) ? b2k : 0.f;
        #pragma unroll
        for (int i = 0; i < 4; ++i) {
          const int node = lq*4 + i;
          const long base = (n0 + node)*(long)(L2C*CH) + s*CH + k;
          out[base] = acc[i] + bb + x[base];
        }
      }
    }
  }
}

// ---------------- launch ----------------
extern "C" void kernel_launch(void* const* d_in, const int* in_sizes, int n_in,
                              void* d_out, int out_size, void* d_ws, size_t ws_size,
                              hipStream_t stream) {
  const float* x      = (const float*)d_in[0];
  // d_in[1] = batch (unused)
  const float* norm_w = (const float*)d_in[2];
  const float* norm_b = (const float*)d_in[3];
  const float* w1     = (const float*)d_in[4];
  const float* b1     = (const float*)d_in[5];
  const float* w_tp   = (const float*)d_in[6];
  const float* w2     = (const float*)d_in[7];
  const float* b2     = (const float*)d_in[8];
  float* out = (float*)d_out;

  const int N = in_sizes[0] / (L2C*CH);   // 6000

  short* wsS = (short*)d_ws;              // ~340 KB
  short* toT = wsS;                       // [96][32]
  short* frT = toT + GPAD*KPAD;           // [32][96]
  short* wb1 = frT + KPAD*GPAD;           // [5][128][128]
  short* wb2 = wb1 + 5*CH*CH;

  build_tables_kernel<<<1, 128, 0, stream>>>(toT, frT);
  convert_w_kernel<<<(5*CH*CH + 255)/256, 256, 0, stream>>>(w1, w2, wb1, wb2);
  eqv3_fused16<<<N/NB, 512, 0, stream>>>(x, norm_w, norm_b, wb1, b1, w_tp, wb2, b2, toT, frT, out);
}

// Round 16
// 94.412 us; speedup vs baseline: 1.2408x; 1.1363x over previous
//
#include <hip/hip_runtime.h>
#include <math.h>

#define L2C 25
#define CH  128
#define NB  16
#define GLB 7
#define GLA 13
#define NG  91
#define GPAD 96
#define KPAD 32
#define HROWS 401   // 400 used rows (=16*25) + 1 pad row

typedef short bf16x8 __attribute__((ext_vector_type(8)));
typedef int   i32x4  __attribute__((ext_vector_type(4)));
typedef float f32x4  __attribute__((ext_vector_type(4)));
typedef unsigned uint2v __attribute__((ext_vector_type(2)));

union frag_u { i32x4 i; bf16x8 h; };

__device__ inline short f2bf(float f) {
  union { float f; unsigned u; } v; v.f = f;
  unsigned r = (v.u + 0x7FFFu + ((v.u >> 16) & 1u)) >> 16;
  return (short)r;
}
__device__ inline unsigned cvt_pk_bf16(float lo, float hi) {
  unsigned r; asm("v_cvt_pk_bf16_f32 %0, %1, %2" : "=v"(r) : "v"(lo), "v"(hi)); return r;
}

// ---------------- SH tables (bf16), built on device ----------------
// Identical math to R8/R13/R15; Newton iteration count cut 64 -> 5 (quadratic
// convergence from cos initial guess reaches fp64 round-off in <=4 iters for n=7).
__global__ void build_tables_kernel(short* __restrict__ toT, short* __restrict__ frT) {
  const int g = threadIdx.x;
  if (g >= GPAD) return;
  const double PI = 3.14159265358979323846;
  double Y[L2C];
  double wg = 0.0;
  if (g < NG) {
    const int b = g / GLA;
    const int a = g % GLA;
    double xx = cos(PI * (b + 0.75) / (GLB + 0.5));
    double pp = 1.0;
    for (int it = 0; it < 5; ++it) {
      double p0 = 1.0, p1 = xx;
      for (int j = 2; j <= GLB; ++j) { double p2 = ((2.0*j-1.0)*xx*p1 - (j-1.0)*p0)/j; p0 = p1; p1 = p2; }
      pp = GLB * (xx*p1 - p0) / (xx*xx - 1.0);
      xx -= p1 / pp;
    }
    { double p0 = 1.0, p1 = xx;
      for (int j = 2; j <= GLB; ++j) { double p2 = ((2.0*j-1.0)*xx*p1 - (j-1.0)*p0)/j; p0 = p1; p1 = p2; }
      pp = GLB * (xx*p1 - p0) / (xx*xx - 1.0); }
    const double wb = 2.0 / ((1.0 - xx*xx) * pp * pp);
    const double ct = xx;
    const double sx = sqrt(fmax(0.0, 1.0 - ct*ct));
    double P[5][5];
    P[0][0] = 1.0;
    for (int m = 1; m <= 4; ++m) P[m][m] = -(2.0*m - 1.0) * sx * P[m-1][m-1];
    for (int m = 0; m <= 3; ++m) P[m+1][m] = (2.0*m + 1.0) * ct * P[m][m];
    for (int m = 0; m <= 4; ++m)
      for (int l = m + 2; l <= 4; ++l)
        P[l][m] = ((2.0*l-1.0)*ct*P[l-1][m] - (l+m-1.0)*P[l-2][m]) / (l - m);
    const double fact[9] = {1,1,2,6,24,120,720,5040,40320};
    const double phi = (2.0*PI/GLA) * a;
    for (int l = 0; l <= 4; ++l)
      for (int m = 0; m <= l; ++m) {
        double Nlm = sqrt((2.0*l+1.0)/(4.0*PI) * fact[l-m]/fact[l+m]);
        if (m == 0) Y[l*l + l] = Nlm * P[l][0];
        else {
          double base = sqrt(2.0) * Nlm * P[l][m];
          Y[l*l + l + m] = base * cos((double)m * phi);
          Y[l*l + l - m] = base * sin((double)m * phi);
        }
      }
    wg = wb * (2.0*PI/GLA);
  }
  for (int l = 0; l < KPAD; ++l) {
    float tv = (g < NG && l < L2C) ? (float)Y[l] : 0.f;
    toT[g*KPAD + l] = f2bf(tv);
  }
  {
    const int hi = g >> 4, r = g & 15;
    const int ksv = hi >> 1, pa = hi & 1;
    const int lqv = r >> 2,  pb = r & 3;
    const int kg = ksv*32 + lqv*8 + pa*4 + pb;
    for (int l = 0; l < KPAD; ++l)
      frT[l*GPAD + kg] = (g < NG && l < L2C) ? f2bf((float)(wg * Y[l])) : (short)0;
  }
}

__global__ void convert_w_kernel(const float* __restrict__ w1, const float* __restrict__ w2,
                                 short* __restrict__ wb1, short* __restrict__ wb2) {
  const int i = blockIdx.x * 256 + threadIdx.x;
  if (i < 5*CH*CH) { wb1[i] = f2bf(w1[i]); wb2[i] = f2bf(w2[i]); }
}

// ==== NB=16 (R15) + dual-stream LN: both nodes loaded/reduced as independent chains ====
__global__ __launch_bounds__(512, 2) void eqv3_fused16(
    const float* __restrict__ x,
    const float* __restrict__ norm_w, const float* __restrict__ norm_b,
    const short* __restrict__ wb1, const float* __restrict__ b1,
    const float* __restrict__ w_tp,
    const short* __restrict__ wb2, const float* __restrict__ b2,
    const short* __restrict__ toT, const short* __restrict__ frT,
    float* __restrict__ out)
{
  __shared__ __align__(16) short u[65536];            // 131,072 B single buffer
  short (*hsh)[HROWS][8] = (short (*)[HROWS][8])u;    // view A: [16][401][8]
  short (*hg)[4][CH][8]  = (short (*)[4][CH][8])u;    // view B: [16][4][128][8]

  const int tid  = threadIdx.x;
  const int w    = tid >> 6;
  const int lane = tid & 63;
  const int l16  = lane & 15;
  const int lq   = lane >> 4;
  const long n0  = (long)blockIdx.x * NB;
  const int k    = w*16 + l16;    // this wave's channel column

  constexpr int LDEG[L2C] = {0,1,1,1,2,2,2,2,2,3,3,3,3,3,3,3,4,4,4,4,4,4,4,4,4};
  constexpr int NT[5]     = {1,3,5,7,9};   // tiles per degree == slots per degree

  // ---- LayerNorm: nodes w and w+8 as two interleaved independent streams ----
  {
    float4 xvA[13], xvB[13];
    const float4* x4A = (const float4*)(x + (n0 + w    )*(long)(L2C*CH));
    const float4* x4B = (const float4*)(x + (n0 + w + 8)*(long)(L2C*CH));
    #pragma unroll
    for (int it = 0; it < 13; ++it) {
      const int j = it*64 + lane;
      if (j < 800) { xvA[it] = x4A[j]; xvB[it] = x4B[j]; }
    }
    float s0A = 0.f, s0qA = 0.f, sqA = 0.f;
    float s0B = 0.f, s0qB = 0.f, sqB = 0.f;
    #pragma unroll
    for (int it = 0; it < 13; ++it) {
      const int j = it*64 + lane;
      if (j < 800) {
        const float tA = xvA[it].x*xvA[it].x + xvA[it].y*xvA[it].y + xvA[it].z*xvA[it].z + xvA[it].w*xvA[it].w;
        const float tB = xvB[it].x*xvB[it].x + xvB[it].y*xvB[it].y + xvB[it].z*xvB[it].z + xvB[it].w*xvB[it].w;
        if (j < 32) {
          s0A += xvA[it].x + xvA[it].y + xvA[it].z + xvA[it].w; s0qA += tA;
          s0B += xvB[it].x + xvB[it].y + xvB[it].z + xvB[it].w; s0qB += tB;
        } else { sqA += tA; sqB += tB; }
      }
    }
    #pragma unroll
    for (int o = 1; o < 64; o <<= 1) {
      s0A  += __shfl_xor(s0A,  o, 64);  s0B  += __shfl_xor(s0B,  o, 64);
      s0qA += __shfl_xor(s0qA, o, 64);  s0qB += __shfl_xor(s0qB, o, 64);
      sqA  += __shfl_xor(sqA,  o, 64);  sqB  += __shfl_xor(sqB,  o, 64);
    }
    const float mean0A = s0A * (1.f/CH);
    const float mean0B = s0B * (1.f/CH);
    const float rstdA  = rsqrtf((sqA + s0qA - CH*mean0A*mean0A) * (1.f/(L2C*CH)) + 1e-5f);
    const float rstdB  = rsqrtf((sqB + s0qB - CH*mean0B*mean0B) * (1.f/(L2C*CH)) + 1e-5f);
    #pragma unroll
    for (int it = 0; it < 13; ++it) {
      const int j = it*64 + lane;
      if (j < 800) {
        const int s = j >> 5;
        const int d = (int)sqrtf((float)s + 0.5f);  // exact floor-sqrt for s<25
        const int c32 = j & 31;
        const int c0  = c32 * 4;
        const float4 nw4 = ((const float4*)norm_w)[d*32 + c32];
        float a0 = xvA[it].x, a1 = xvA[it].y, a2 = xvA[it].z, a3 = xvA[it].w;
        float b0 = xvB[it].x, b1v = xvB[it].y, b2v = xvB[it].z, b3 = xvB[it].w;
        if (s == 0) {
          const float4 nb4 = ((const float4*)norm_b)[c32];
          a0 = (a0 - mean0A)*rstdA*nw4.x + nb4.x;
          a1 = (a1 - mean0A)*rstdA*nw4.y + nb4.y;
          a2 = (a2 - mean0A)*rstdA*nw4.z + nb4.z;
          a3 = (a3 - mean0A)*rstdA*nw4.w + nb4.w;
          b0 = (b0 - mean0B)*rstdB*nw4.x + nb4.x;
          b1v = (b1v - mean0B)*rstdB*nw4.y + nb4.y;
          b2v = (b2v - mean0B)*rstdB*nw4.z + nb4.z;
          b3 = (b3 - mean0B)*rstdB*nw4.w + nb4.w;
        } else {
          a0 *= rstdA*nw4.x; a1 *= rstdA*nw4.y; a2 *= rstdA*nw4.z; a3 *= rstdA*nw4.w;
          b0 *= rstdB*nw4.x; b1v *= rstdB*nw4.y; b2v *= rstdB*nw4.z; b3 *= rstdB*nw4.w;
        }
        uint2v pkA; pkA[0] = cvt_pk_bf16(a0, a1); pkA[1] = cvt_pk_bf16(a2, a3);
        uint2v pkB; pkB[0] = cvt_pk_bf16(b0, b1v); pkB[1] = cvt_pk_bf16(b2v, b3);
        *(uint2v*)&hsh[c0 >> 3][16*s + w    ][c0 & 7] = pkA;
        *(uint2v*)&hsh[c0 >> 3][16*s + w + 8][c0 & 7] = pkB;
      }
    }
  }
  __syncthreads();   // (1) LN staged (all 400 rows written)

  // ---- linear1: 25 full tiles (tile == slot), accumulate packed bf16 pairs ----
  unsigned pk1[L2C][2];
  {
    const float b1k = b1[k];
    int s = 0;
    #pragma unroll
    for (int d = 0; d < 5; ++d) {
      frag_u B[4];
      #pragma unroll
      for (int ks = 0; ks < 4; ++ks)
        B[ks].i = *(const i32x4*)(wb1 + ((d*CH + k)*CH + ks*32 + lq*8));
      #pragma unroll
      for (int mt = 0; mt < NT[d]; ++mt, ++s) {
        f32x4 acc = {0.f, 0.f, 0.f, 0.f};
        #pragma unroll
        for (int ks = 0; ks < 4; ++ks) {
          const bf16x8 a = *(const bf16x8*)&hsh[ks*4 + lq][16*s + l16][0];
          acc = __builtin_amdgcn_mfma_f32_16x16x32_bf16(a, B[ks].h, acc, 0, 0, 0);
        }
        const float bb = (s == 0) ? b1k : 0.f;
        pk1[s][0] = cvt_pk_bf16(acc[0] + bb, acc[1] + bb);
        pk1[s][1] = cvt_pk_bf16(acc[2] + bb, acc[3] + bb);
      }
    }
  }
  __syncthreads();   // (2) ALL lin1 reads complete; buffer reusable in hg view

  // ---- write lin1 output (hg view); lane owns nodes lq*4..lq*4+3, column k ----
  {
    const i32x4 z = {0,0,0,0};
    #pragma unroll
    for (int j = 0; j < 4; ++j)
      *(i32x4*)&hg[lq*4 + j][3][k][0] = z;   // zero slots 24..31 for OWN nodes (24 rewritten)
    #pragma unroll
    for (int s = 0; s < L2C; ++s) {
      const int nb = lq*4;
      hg[nb+0][s >> 3][k][s & 7] = (short)(pk1[s][0] & 0xFFFFu);
      hg[nb+1][s >> 3][k][s & 7] = (short)(pk1[s][0] >> 16);
      hg[nb+2][s >> 3][k][s & 7] = (short)(pk1[s][1] & 0xFFFFu);
      hg[nb+3][s >> 3][k][s & 7] = (short)(pk1[s][1] >> 16);
    }
  }

  // ---- Bh prefetch: own k columns (no barrier needed) ----
  frag_u Bh[NB];
  #pragma unroll
  for (int n = 0; n < NB; ++n)
    Bh[n].i = *(const i32x4*)&hg[n][lq][k][0];
  __syncthreads();   // (3) all hg reads done; Gaunt may write buffer in hsh view

  // ---- Gaunt: 2 independent node streams (n, n+8); register from-grid handoff (R8) ----
  {
    frag_u Ato[6];
    #pragma unroll
    for (int gt = 0; gt < 6; ++gt)
      Ato[gt].i = *(const i32x4*)(toT + (gt*16 + l16)*KPAD + lq*8);
    frag_u Afr[2][3];
    #pragma unroll
    for (int mt = 0; mt < 2; ++mt)
      #pragma unroll
      for (int ks = 0; ks < 3; ++ks)
        Afr[mt][ks].i = *(const i32x4*)(frT + (mt*16 + l16)*GPAD + ks*32 + lq*8);

    float wtp[2][4]; int hrowb[2][4];
    #pragma unroll
    for (int mt = 0; mt < 2; ++mt)
      #pragma unroll
      for (int i = 0; i < 4; ++i) {
        const int l = mt*16 + lq*4 + i;
        if (l < L2C) {
          wtp[mt][i]   = w_tp[LDEG[l]*CH + k];
          hrowb[mt][i] = 16*l;                 // NB=16: row = 16*l + node
        } else { wtp[mt][i] = 0.f; hrowb[mt][i] = -1; }
      }

    #pragma unroll
    for (int np = 0; np < 8; ++np) {
      const int nA = np, nB2 = np + 8;
      unsigned pA[6][2], pB[6][2];
      #pragma unroll
      for (int gt = 0; gt < 6; ++gt) {
        f32x4 aA = {0.f,0.f,0.f,0.f}, aB = {0.f,0.f,0.f,0.f};
        aA = __builtin_amdgcn_mfma_f32_16x16x32_bf16(Ato[gt].h, Bh[nA].h,  aA, 0, 0, 0);
        aB = __builtin_amdgcn_mfma_f32_16x16x32_bf16(Ato[gt].h, Bh[nB2].h, aB, 0, 0, 0);
        pA[gt][0] = cvt_pk_bf16(aA[0]*aA[0], aA[1]*aA[1]);
        pA[gt][1] = cvt_pk_bf16(aA[2]*aA[2], aA[3]*aA[3]);
        pB[gt][0] = cvt_pk_bf16(aB[0]*aB[0], aB[1]*aB[1]);
        pB[gt][1] = cvt_pk_bf16(aB[2]*aB[2], aB[3]*aB[3]);
      }
      f32x4 acc2A[2] = {{0.f,0.f,0.f,0.f},{0.f,0.f,0.f,0.f}};
      f32x4 acc2B[2] = {{0.f,0.f,0.f,0.f},{0.f,0.f,0.f,0.f}};
      #pragma unroll
      for (int ks = 0; ks < 3; ++ks) {
        frag_u BgA, BgB;
        BgA.i[0] = (int)pA[2*ks][0];   BgA.i[1] = (int)pA[2*ks][1];
        BgA.i[2] = (int)pA[2*ks+1][0]; BgA.i[3] = (int)pA[2*ks+1][1];
        BgB.i[0] = (int)pB[2*ks][0];   BgB.i[1] = (int)pB[2*ks][1];
        BgB.i[2] = (int)pB[2*ks+1][0]; BgB.i[3] = (int)pB[2*ks+1][1];
        acc2A[0] = __builtin_amdgcn_mfma_f32_16x16x32_bf16(Afr[0][ks].h, BgA.h, acc2A[0], 0, 0, 0);
        acc2A[1] = __builtin_amdgcn_mfma_f32_16x16x32_bf16(Afr[1][ks].h, BgA.h, acc2A[1], 0, 0, 0);
        acc2B[0] = __builtin_amdgcn_mfma_f32_16x16x32_bf16(Afr[0][ks].h, BgB.h, acc2B[0], 0, 0, 0);
        acc2B[1] = __builtin_amdgcn_mfma_f32_16x16x32_bf16(Afr[1][ks].h, BgB.h, acc2B[1], 0, 0, 0);
      }
      #pragma unroll
      for (int mt = 0; mt < 2; ++mt)
        #pragma unroll
        for (int i = 0; i < 4; ++i)
          if (hrowb[mt][i] >= 0) {
            hsh[k >> 3][hrowb[mt][i] + nA][k & 7]  = f2bf(acc2A[mt][i] * wtp[mt][i]);
            hsh[k >> 3][hrowb[mt][i] + nB2][k & 7] = f2bf(acc2B[mt][i] * wtp[mt][i]);
          }
    }
  }
  __syncthreads();   // (4) Gaunt output staged (hsh view)

  // ---- linear2: 25 full tiles + bias(l=0) + residual -> direct global store ----
  {
    const float b2k = b2[k];
    int s = 0;
    #pragma unroll
    for (int d = 0; d < 5; ++d) {
      frag_u B[4];
      #pragma unroll
      for (int ks = 0; ks < 4; ++ks)
        B[ks].i = *(const i32x4*)(wb2 + ((d*CH + k)*CH + ks*32 + lq*8));
      #pragma unroll
      for (int mt = 0; mt < NT[d]; ++mt, ++s) {
        f32x4 acc = {0.f, 0.f, 0.f, 0.f};
        #pragma unroll
        for (int ks = 0; ks < 4; ++ks) {
          const bf16x8 a = *(const bf16x8*)&hsh[ks*4 + lq][16*s + l16][0];
          acc = __builtin_amdgcn_mfma_f32_16x16x32_bf16(a, B[ks].h, acc, 0, 0, 0);
        }
        const float bb = (s == 0) ? b2k : 0.f;
        #pragma unroll
        for (int i = 0; i < 4; ++i) {
          const int node = lq*4 + i;
          const long base = (n0 + node)*(long)(L2C*CH) + s*CH + k;
          out[base] = acc[i] + bb + x[base];
        }
      }
    }
  }
}

// ---------------- launch ----------------
extern "C" void kernel_launch(void* const* d_in, const int* in_sizes, int n_in,
                              void* d_out, int out_size, void* d_ws, size_t ws_size,
                              hipStream_t stream) {
  const float* x      = (const float*)d_in[0];
  // d_in[1] = batch (unused)
  const float* norm_w = (const float*)d_in[2];
  const float* norm_b = (const float*)d_in[3];
  const float* w1     = (const float*)d_in[4];
  const float* b1     = (const float*)d_in[5];
  const float* w_tp   = (const float*)d_in[6];
  const float* w2     = (const float*)d_in[7];
  const float* b2     = (const float*)d_in[8];
  float* out = (float*)d_out;

  const int N = in_sizes[0] / (L2C*CH);   // 6000

  short* wsS = (short*)d_ws;              // ~340 KB
  short* toT = wsS;                       // [96][32]
  short* frT = toT + GPAD*KPAD;           // [32][96]
  short* wb1 = frT + KPAD*GPAD;           // [5][128][128]
  short* wb2 = wb1 + 5*CH*CH;

  build_tables_kernel<<<1, 128, 0, stream>>>(toT, frT);
  convert_w_kernel<<<(5*CH*CH + 255)/256, 256, 0, stream>>>(w1, w2, wb1, wb2);
  eqv3_fused16<<<N/NB, 512, 0, stream>>>(x, norm_w, norm_b, wb1, b1, w_tp, wb2, b2, toT, frT, out);
}